// Round 3
// baseline (452.737 us; speedup 1.0000x reference)
//
#include <hip/hip_runtime.h>
#include <hip/hip_bf16.h>

#define NQ 10000
#define BS 6
#define NV 30825   // 23200 + 5800 + 1450 + 375

typedef __attribute__((ext_vector_type(8))) short bf16x8;
typedef __attribute__((ext_vector_type(8))) unsigned short u16x8;
typedef __attribute__((ext_vector_type(4))) float f32x4;
typedef __attribute__((ext_vector_type(2))) float f32x2;

__device__ __forceinline__ void gload_lds16(const void* g, void* l) {
  __builtin_amdgcn_global_load_lds(
      (const __attribute__((address_space(1))) unsigned int*)g,
      (__attribute__((address_space(3))) unsigned int*)l, 16, 0, 0);
}

__device__ __forceinline__ unsigned short bf_bits(float f) {
  __hip_bfloat16 h = __float2bfloat16(f);
  return *(unsigned short*)&h;
}

// ---------------------------------------------------------------------------
// Pack + transpose weights to bf16:
//   wvalT [256][256]  = w_val^T
//   wpackT[768][256]  = concat(w_off, w_attn)^T
//   bpack [768]       = concat(b_off, b_attn)
// ---------------------------------------------------------------------------
__global__ __launch_bounds__(256) void prep_weights_kernel(
    const float* __restrict__ w_val, const float* __restrict__ w_off,
    const float* __restrict__ w_attn, const float* __restrict__ b_off,
    const float* __restrict__ b_attn, unsigned short* __restrict__ wvalT,
    unsigned short* __restrict__ wpackT, float* __restrict__ bpack) {
  int i = blockIdx.x * 256 + threadIdx.x;
  if (i < 65536) {
    int n = i >> 8, k = i & 255;
    wvalT[i] = bf_bits(w_val[k * 256 + n]);
  } else if (i < 65536 + 196608) {
    int j = i - 65536;
    int n = j >> 8, k = j & 255;
    float v = (n < 512) ? w_off[k * 512 + n] : w_attn[k * 256 + (n - 512)];
    wpackT[j] = bf_bits(v);
  } else if (i < 65536 + 196608 + 768) {
    int j = i - 262144;
    bpack[j] = (j < 512) ? b_off[j] : b_attn[j - 512];
  }
}

// ---------------------------------------------------------------------------
// MFMA GEMM with fused A conversion:
//   C[M,N](bf16) = bf16(A[M,256] f32) @ WT[N,256]^T(bf16) + bias[N](f32)
// 128x128 tile, BK=64, 4 waves (2x2 of 64x64).
// A: reg-staged f32->bf16 (coalesced float4 x2 per thread, ds_write_b128).
// B: global_load_lds width 16.  Requires N % 128 == 0.
// ---------------------------------------------------------------------------
__global__ __launch_bounds__(256) void gemm_mfma_kernel(
    const float* __restrict__ A, const unsigned short* __restrict__ WT,
    const float* __restrict__ bias, unsigned short* __restrict__ C, int M, int N) {
  __shared__ short As[128 * 64];  // [row][k] bf16, 128B rows
  __shared__ short Bs[128 * 64];  // [col][k] bf16, 128B rows (WT layout)
  const int tid = threadIdx.x;
  const int wv = tid >> 6;
  const int lane = tid & 63;
  const int wr = wv >> 1, wc = wv & 1;
  const int m0 = blockIdx.x * 128;
  const int n0 = blockIdx.y * 128;

  f32x4 acc[4][4] = {};

  for (int kt = 0; kt < 4; ++kt) {
    // B tile via async global->LDS
#pragma unroll
    for (int j = 0; j < 4; ++j) {
      int u = j * 256 + tid;
      int row = u >> 3;
      int kbyte = (u & 7) * 16;
      int ldsoff = (j * 256 + wv * 64) * 16;  // wave-uniform base (bytes)
      gload_lds16((const char*)WT + (size_t)(n0 + row) * 512 + kt * 128 + kbyte,
                  (char*)Bs + ldsoff);
    }
    // A tile: f32 load + convert + LDS write (fused conversion)
#pragma unroll
    for (int j = 0; j < 4; ++j) {
      int u = j * 256 + tid;
      int row = u >> 3, oct = u & 7;
      int gr = m0 + row; if (gr >= M) gr = M - 1;
      const float4* ap = (const float4*)(A + (size_t)gr * 256 + kt * 64 + oct * 8);
      float4 a0 = ap[0], a1 = ap[1];
      u16x8 pk = { bf_bits(a0.x), bf_bits(a0.y), bf_bits(a0.z), bf_bits(a0.w),
                   bf_bits(a1.x), bf_bits(a1.y), bf_bits(a1.z), bf_bits(a1.w) };
      *(u16x8*)&As[row * 64 + oct * 8] = pk;
    }
    __syncthreads();
#pragma unroll
    for (int kk = 0; kk < 2; ++kk) {
      bf16x8 af[4], bfr[4];
#pragma unroll
      for (int mi = 0; mi < 4; ++mi) {
        int off = (wr * 64 + mi * 16 + (lane & 15)) * 64 + kk * 32 + (lane >> 4) * 8;
        af[mi] = *(const bf16x8*)&As[off];
      }
#pragma unroll
      for (int ni = 0; ni < 4; ++ni) {
        int off = (wc * 64 + ni * 16 + (lane & 15)) * 64 + kk * 32 + (lane >> 4) * 8;
        bfr[ni] = *(const bf16x8*)&Bs[off];
      }
#pragma unroll
      for (int mi = 0; mi < 4; ++mi)
#pragma unroll
        for (int ni = 0; ni < 4; ++ni)
          acc[mi][ni] = __builtin_amdgcn_mfma_f32_16x16x32_bf16(
              af[mi], bfr[ni], acc[mi][ni], 0, 0, 0);
    }
    __syncthreads();
  }

  const int colb = n0 + wc * 64 + (lane & 15);
  float bvn[4];
#pragma unroll
  for (int ni = 0; ni < 4; ++ni) bvn[ni] = bias[colb + ni * 16];
#pragma unroll
  for (int mi = 0; mi < 4; ++mi) {
#pragma unroll
    for (int r = 0; r < 4; ++r) {
      int row = m0 + wr * 64 + mi * 16 + (lane >> 4) * 4 + r;
      if (row < M) {
#pragma unroll
        for (int ni = 0; ni < 4; ++ni)
          C[(size_t)row * N + colb + ni * 16] = bf_bits(acc[mi][ni][r] + bvn[ni]);
      }
    }
  }
}

// ---------------------------------------------------------------------------
// Sampling kernel:
//  phase 1: 256 threads = 256 (head,level,point) samples; softmax + bilinear
//           setup once per sample -> s_idx/s_w (split arrays, conflict-free).
//  phase 2: 256 threads = 8 heads x 8 sample-groups x 4 channel-octs.
//           Each lane: 8 channels (one dwordx4/gather) x 4 samples x 4 corners
//           = 16 loads of 16B. shfl_xor reduce over sample-groups.
// ---------------------------------------------------------------------------
__global__ __launch_bounds__(256) void msda_sample_kernel(
    const __hip_bfloat16* __restrict__ vproj,  // [BS*NV, 256] bf16
    const __hip_bfloat16* __restrict__ C2,     // [BS*NQ, 768]: 512 off | 256 attn
    const float* __restrict__ ref,             // [BS*NQ, 4, 2]
    float* __restrict__ out) {                 // [BS*NQ, 256]
  const int bq = blockIdx.x;
  const int b = bq / NQ;
  const int tid = threadIdx.x;

  __shared__ int   s_idx[4][256];
  __shared__ float s_w[4][256];

  {  // ---- phase 1 : one sample per thread ----
    const int lp = tid & 31;
    const int l = lp >> 3, p = lp & 7, z = p & 3;
    const __hip_bfloat162* offp = (const __hip_bfloat162*)(C2 + (size_t)bq * 768);
    __hip_bfloat162 ob = offp[tid];
    float ox = __bfloat162float(ob.x), oy = __bfloat162float(ob.y);
    float logit = __bfloat162float(C2[(size_t)bq * 768 + 512 + tid]);

    float mx = logit;
#pragma unroll
    for (int m = 16; m >= 1; m >>= 1) mx = fmaxf(mx, __shfl_xor(mx, m, 32));
    float e = __expf(logit - mx);
    float s = e;
#pragma unroll
    for (int m = 16; m >= 1; m >>= 1) s += __shfl_xor(s, m, 32);
    float aw = e / s;

    float2 rz = *(const float2*)(ref + (size_t)bq * 8 + z * 2);
    const int W = 200 >> l;
    const int H = (l == 3) ? 15 : (116 >> l);
    const int base = (l == 0) ? 0 : (l == 1) ? 23200 : (l == 2) ? 29000 : 30450;

    float x = rz.x * (float)W + ox - 0.5f;
    float y = rz.y * (float)H + oy - 0.5f;
    float x0f = floorf(x), y0f = floorf(y);
    float lx = x - x0f, ly = y - y0f;
    int x0 = (int)x0f, y0 = (int)y0f;
    int x1 = x0 + 1, y1 = y0 + 1;

    float w00 = (1.f - ly) * (1.f - lx) * aw;
    float w01 = (1.f - ly) * lx * aw;
    float w10 = ly * (1.f - lx) * aw;
    float w11 = ly * lx * aw;

    if (!((x0 >= 0) & (x0 < W))) { w00 = 0.f; w10 = 0.f; }
    if (!((x1 >= 0) & (x1 < W))) { w01 = 0.f; w11 = 0.f; }
    if (!((y0 >= 0) & (y0 < H))) { w00 = 0.f; w01 = 0.f; }
    if (!((y1 >= 0) & (y1 < H))) { w10 = 0.f; w11 = 0.f; }

    int x0c = min(max(x0, 0), W - 1);
    int x1c = min(max(x1, 0), W - 1);
    int y0c = min(max(y0, 0), H - 1);
    int y1c = min(max(y1, 0), H - 1);

    s_idx[0][tid] = base + y0c * W + x0c;  s_w[0][tid] = w00;
    s_idx[1][tid] = base + y0c * W + x1c;  s_w[1][tid] = w01;
    s_idx[2][tid] = base + y1c * W + x0c;  s_w[2][tid] = w10;
    s_idx[3][tid] = base + y1c * W + x1c;  s_w[3][tid] = w11;
  }
  __syncthreads();

  // ---- phase 2 : gather 8 channels per lane ----
  const int h = tid >> 5;
  const int lane32 = tid & 31;
  const int e = lane32 & 3;        // channel oct: ch = e*8 .. e*8+8
  const int sibase = tid & ~3;     // h*32 + sg*4
  const char* vrow = (const char*)vproj + (size_t)b * NV * 512 + h * 64 + e * 16;

  f32x2 acc0 = {0.f, 0.f}, acc1 = {0.f, 0.f}, acc2 = {0.f, 0.f}, acc3 = {0.f, 0.f};
#pragma unroll
  for (int s = 0; s < 4; ++s) {
    const int si = sibase + s;
#pragma unroll
    for (int c = 0; c < 4; ++c) {
      int row = s_idx[c][si];
      float w = s_w[c][si];
      uint4 v = *(const uint4*)(vrow + (row << 9));
      f32x2 wv = {w, w};
      f32x2 p0 = {__uint_as_float(v.x << 16), __uint_as_float(v.x & 0xffff0000u)};
      f32x2 p1 = {__uint_as_float(v.y << 16), __uint_as_float(v.y & 0xffff0000u)};
      f32x2 p2 = {__uint_as_float(v.z << 16), __uint_as_float(v.z & 0xffff0000u)};
      f32x2 p3 = {__uint_as_float(v.w << 16), __uint_as_float(v.w & 0xffff0000u)};
      acc0 += wv * p0;
      acc1 += wv * p1;
      acc2 += wv * p2;
      acc3 += wv * p3;
    }
  }

  // reduce over the 8 sample-groups (xor masks 4, 8, 16 within 32-lane group)
#pragma unroll
  for (int m = 4; m <= 16; m <<= 1) {
    acc0.x += __shfl_xor(acc0.x, m, 32);  acc0.y += __shfl_xor(acc0.y, m, 32);
    acc1.x += __shfl_xor(acc1.x, m, 32);  acc1.y += __shfl_xor(acc1.y, m, 32);
    acc2.x += __shfl_xor(acc2.x, m, 32);  acc2.y += __shfl_xor(acc2.y, m, 32);
    acc3.x += __shfl_xor(acc3.x, m, 32);  acc3.y += __shfl_xor(acc3.y, m, 32);
  }

  if (lane32 < 4) {
    float4* op = (float4*)(out + (size_t)bq * 256 + h * 32 + e * 8);
    op[0] = make_float4(acc0.x, acc0.y, acc1.x, acc1.y);
    op[1] = make_float4(acc2.x, acc2.y, acc3.x, acc3.y);
  }
}

extern "C" void kernel_launch(void* const* d_in, const int* in_sizes, int n_in,
                              void* d_out, int out_size, void* d_ws, size_t ws_size,
                              hipStream_t stream) {
  const float* query  = (const float*)d_in[0];
  const float* value  = (const float*)d_in[1];
  const float* refp   = (const float*)d_in[2];
  const float* w_off  = (const float*)d_in[3];
  const float* b_off  = (const float*)d_in[4];
  const float* w_attn = (const float*)d_in[5];
  const float* b_attn = (const float*)d_in[6];
  const float* w_val  = (const float*)d_in[7];
  const float* b_val  = (const float*)d_in[8];
  float* out = (float*)d_out;

  char* ws = (char*)d_ws;
  // layout (bytes):
  //   vproj  bf16 [184950*256]  @ 0           (94,694,400)
  //   C2     bf16 [60000*768]   @ 94,694,400  (92,160,000)
  //   wvalT  bf16 [256*256]     @ 186,854,400 (131,072)
  //   wpackT bf16 [768*256]     @ 186,985,472 (393,216)
  //   bpack  f32  [768]         @ 187,378,688 (3,072)
  unsigned short* vproj  = (unsigned short*)(ws);
  unsigned short* C2     = (unsigned short*)(ws + 94694400);
  unsigned short* wvalT  = (unsigned short*)(ws + 186854400);
  unsigned short* wpackT = (unsigned short*)(ws + 186985472);
  float*          bpack  = (float*)        (ws + 187378688);

  const int Mv = BS * NV;  // 184950
  const int Mq = BS * NQ;  // 60000

  prep_weights_kernel<<<1032, 256, 0, stream>>>(w_val, w_off, w_attn, b_off, b_attn,
                                                wvalT, wpackT, bpack);
  gemm_mfma_kernel<<<dim3((Mv + 127) / 128, 2), 256, 0, stream>>>(
      value, wvalT, b_val, vproj, Mv, 256);
  gemm_mfma_kernel<<<dim3((Mq + 127) / 128, 6), 256, 0, stream>>>(
      query, wpackT, bpack, C2, Mq, 768);
  msda_sample_kernel<<<BS * NQ, 256, 0, stream>>>(
      (const __hip_bfloat16*)vproj, (const __hip_bfloat16*)C2, refp, out);
}